// Round 10
// baseline (225.804 us; speedup 1.0000x reference)
//
#include <hip/hip_runtime.h>
#include <stdint.h>

// Problem: B=2, S=2048, D=1024, H=16, HD=64.
// Reference dtype fp32; harness may deliver fp32 OR bf16. Runtime-detected.
#define Bb 2
#define Ss 2048
#define Dd 1024
#define Hh 16
#define HD 64
#define Mtot 4096  // B*S

typedef __bf16 bf16x8 __attribute__((ext_vector_type(8)));
typedef float f32x4 __attribute__((ext_vector_type(4)));
typedef unsigned short ushort_t;

#if __has_builtin(__builtin_amdgcn_exp2f)
#define EXP2(x) __builtin_amdgcn_exp2f(x)   // single v_exp_f32
#else
#define EXP2(x) __expf((x) * 0.6931472f)
#endif

__device__ __forceinline__ float bf2f(ushort_t u) {
    union { uint32_t i; float f; } v;
    v.i = ((uint32_t)u) << 16;
    return v.f;
}

__device__ __forceinline__ ushort_t f2bf(float f) {
    union { float f; uint32_t i; } v;
    v.f = f;
    uint32_t u = v.i;
    u += 0x7FFFu + ((u >> 16) & 1u);  // round-to-nearest-even
    return (ushort_t)(u >> 16);
}

__device__ __forceinline__ uint32_t fbits(float f) {
    union { float f; uint32_t i; } v; v.f = f; return v.i;
}

__device__ __forceinline__ float load_in(const void* p, size_t i, int isf32) {
    if (isf32) return ((const float*)p)[i];
    return bf2f(((const ushort_t*)p)[i]);
}

// async global->LDS, 16B per lane; LDS dest = wave-uniform base + lane*16 (HW)
__device__ __forceinline__ void gload_lds16(const void* g, void* l) {
    __builtin_amdgcn_global_load_lds(
        (const __attribute__((address_space(1))) void*)g,
        (__attribute__((address_space(3))) void*)l, 16, 0, 0);
}

// ---------------------------------------------------------------------------
// Kernel P: fused prep. Blocks 0..1023: convert X/mask/vectors to bf16.
// Blocks 1024..5119: transpose+convert weights W[K][N] -> wt[N][K].
// Every block self-detects input dtype from X's first 2048 ushorts.
// ---------------------------------------------------------------------------
#define NCONV 4204544ull
__global__ __launch_bounds__(256) void prep_k(
    const void* X, const void* mask, const void* bq, const void* bk,
    const void* bv, const void* bo, const void* g, const void* be,
    const void* Wq, const void* Wk, const void* Wv, const void* Wo,
    int* __restrict__ flag, ushort_t* __restrict__ cX,
    ushort_t* __restrict__ cMask, ushort_t* __restrict__ cB,
    ushort_t* __restrict__ wt) {
    __shared__ int sflag;
    __shared__ ushort_t tile[32][33];
    const int tid = threadIdx.x;
    {
        const int lane = tid & 63;
        if (tid < 64) {
            const ushort_t* Xu = (const ushort_t*)X;
            int local = 0;
            for (int i = lane; i < 2048; i += 64) {
                int e = (Xu[i] >> 7) & 0xFF;
                local += (e >= 0x90);
            }
            for (int off = 1; off < 64; off <<= 1) local += __shfl_xor(local, off);
            if (lane == 0) sflag = (local >= 4) ? 1 : 0;
        }
    }
    __syncthreads();
    const int f = sflag;
    if (blockIdx.x == 0 && tid == 0) *flag = f;

    if (blockIdx.x < 1024) {
        const size_t stride = 1024ull * 256ull;
        for (size_t i = (size_t)blockIdx.x * 256 + tid; i < NCONV; i += stride) {
            if (i < 4194304ull) {
                cX[i] = f2bf(load_in(X, i, f));
            } else if (i < 4198400ull) {
                size_t j = i - 4194304ull;
                cMask[j] = f2bf(load_in(mask, j, f));
            } else {
                size_t j = i - 4198400ull;
                int w = (int)(j >> 10);
                size_t r = j & 1023ull;
                const void* p = (w == 0) ? bq : (w == 1) ? bk : (w == 2) ? bv
                              : (w == 3) ? bo : (w == 4) ? g : be;
                cB[w * 1024 + r] = f2bf(load_in(p, r, f));
            }
        }
    } else {
        int id2 = blockIdx.x - 1024;
        int z = id2 >> 10;
        int rem = id2 & 1023;
        int bx = rem & 31, by = rem >> 5;
        const void* W = (z == 0) ? Wq : (z == 1) ? Wk : (z == 2) ? Wv : Wo;
        ushort_t* T = wt + (size_t)z * Dd * Dd;
        int tx = tid & 31, ty = tid >> 5;
        int x = bx * 32 + tx;
        int y0 = by * 32;
        for (int i = 0; i < 4; i++) {
            int y = y0 + ty + i * 8;
            tile[ty + i * 8][tx] = f2bf(load_in(W, (size_t)y * Dd + x, f));
        }
        __syncthreads();
        int x2 = by * 32 + tx;
        int y20 = bx * 32;
        for (int i = 0; i < 4; i++) {
            int y = y20 + ty + i * 8;
            T[(size_t)y * Dd + x2] = tile[tx][ty + i * 8];
        }
    }
}

// ---------------------------------------------------------------------------
// Kernel 1: fused QKV projection. grid=(N/128, M/128, 3), block=256 (4 waves)
// Double-buffered global_load_lds(16B) staging. Q pre-scaled by 0.125*log2e.
// Epilogue: Q/K direct register stores (scatter theory disproven r6);
// V^T via LDS transpose (2B x 4KB-stride scatter IS real there).
// Q,K: [B,H,S,HD]; V transposed: [B,H,HD,S].
// ---------------------------------------------------------------------------
__global__ __launch_bounds__(256) void gemm_qkv(
    const ushort_t* __restrict__ X, const ushort_t* __restrict__ wt,
    const ushort_t* __restrict__ cB,
    ushort_t* __restrict__ Qb, ushort_t* __restrict__ Kb, ushort_t* __restrict__ Vtb) {
    const int z = blockIdx.z;
    const ushort_t* Wt = wt + (size_t)z * Dd * Dd;
    const ushort_t* bias = cB + z * 1024;

    __shared__ __align__(16) ushort_t smem[2][2][128 * 32];  // 32 KB

    const int tid = threadIdx.x;
    const int lane = tid & 63, wv = tid >> 6;
    const int quad = lane >> 4, l15 = lane & 15;
    const int wrow = (wv >> 1) * 64, wcol = (wv & 1) * 64;
    const int row0 = blockIdx.y * 128, col0 = blockIdx.x * 128;
    const int lrow = lane >> 2, lcol = (lane & 3) * 8;

    const f32x4 fzero = {0.f, 0.f, 0.f, 0.f};
    f32x4 acc[4][4];
    for (int mt = 0; mt < 4; mt++)
        for (int nt = 0; nt < 4; nt++) acc[mt][nt] = fzero;

    for (int j = 0; j < 2; j++) {
        int ch = wv * 2 + j;
        gload_lds16(&X[(size_t)(row0 + ch * 16 + lrow) * Dd + lcol],
                    &smem[0][0][ch * 512]);
        gload_lds16(&Wt[(size_t)(col0 + ch * 16 + lrow) * Dd + lcol],
                    &smem[0][1][ch * 512]);
    }

    for (int k0 = 0; k0 < Dd; k0 += 32) {
        const int buf = (k0 >> 5) & 1;
        __syncthreads();
        if (k0 + 32 < Dd) {
            for (int j = 0; j < 2; j++) {
                int ch = wv * 2 + j;
                gload_lds16(&X[(size_t)(row0 + ch * 16 + lrow) * Dd + k0 + 32 + lcol],
                            &smem[buf ^ 1][0][ch * 512]);
                gload_lds16(&Wt[(size_t)(col0 + ch * 16 + lrow) * Dd + k0 + 32 + lcol],
                            &smem[buf ^ 1][1][ch * 512]);
            }
        }
        const ushort_t* As = &smem[buf][0][0];
        const ushort_t* Bs = &smem[buf][1][0];
        bf16x8 af[4], bfr[4];
        for (int mt = 0; mt < 4; mt++)
            af[mt] = *(const bf16x8*)(&As[(wrow + mt * 16 + l15) * 32 + quad * 8]);
        for (int nt = 0; nt < 4; nt++)
            bfr[nt] = *(const bf16x8*)(&Bs[(wcol + nt * 16 + l15) * 32 + quad * 8]);
        for (int mt = 0; mt < 4; mt++)
            for (int nt = 0; nt < 4; nt++)
                acc[mt][nt] = __builtin_amdgcn_mfma_f32_16x16x32_bf16(
                    af[mt], bfr[nt], acc[mt][nt], 0, 0, 0);
    }

    const float qscale = 0.18033688f;  // 0.125 * log2(e)
    if (z != 2) {
        // direct register stores: 32B segments x4 per instr, no barriers
        ushort_t* Ob = (z == 0) ? Qb : Kb;
        for (int mt = 0; mt < 4; mt++)
            for (int nt = 0; nt < 4; nt++) {
                int gn = col0 + wcol + nt * 16 + l15;
                int h = gn >> 6, d = gn & 63;
                float bv_ = bf2f(bias[gn]);
                for (int r = 0; r < 4; r++) {
                    int gm = row0 + wrow + mt * 16 + quad * 4 + r;
                    float v = acc[mt][nt][r] + bv_;
                    if (z == 0) v *= qscale;
                    int b = gm >> 11, s = gm & 2047;
                    Ob[((size_t)((b * Hh + h) * Ss + s)) * HD + d] = f2bf(v);
                }
            }
    } else {
        // V^T: per-mt 32x128 chunk via LDS, coalesced 32B stores
        ushort_t* Cs = &smem[0][0][0];
        for (int mt = 0; mt < 4; mt++) {
            __syncthreads();
            for (int nt = 0; nt < 4; nt++) {
                int gn = col0 + wcol + nt * 16 + l15;
                float bv_ = bf2f(bias[gn]);
                for (int r = 0; r < 4; r++) {
                    float v = acc[mt][nt][r] + bv_;
                    int ric = (wv >> 1) * 16 + quad * 4 + r;
                    Cs[ric * 136 + wcol + nt * 16 + l15] = f2bf(v);
                }
            }
            __syncthreads();
            int c = tid >> 1, r0 = (tid & 1) * 16;
            int gn = col0 + c, h = gn >> 6, d = gn & 63;
            int gmbase = row0 + (r0 >> 4) * 64 + mt * 16;
            int b = gmbase >> 11, s0 = gmbase & 2047;
            union { ushort_t u[16]; uint4 q[2]; } pk;
            for (int i = 0; i < 16; i++) pk.u[i] = Cs[(r0 + i) * 136 + c];
            uint4* dst = (uint4*)&Vtb[((size_t)((b * Hh + h) * HD + d)) * Ss + s0];
            dst[0] = pk.q[0];
            dst[1] = pk.q[1];
        }
    }
}

// ---------------------------------------------------------------------------
// Kernel 2: split-K flash attention. grid=(B*H, S/128, 2), block=512.
// Streaming softmax (fixed shift) is associative across key ranges: each
// block covers 1024 keys, writes UN-normalized partial o (bf16) + l (f32).
// combine_k sums halves and normalizes. maskF only 4KB/half ->
// LDS 45.2KB -> 3 blocks/CU with 1024 blocks to fill them.
// ---------------------------------------------------------------------------
#define STR 36
#define KHALF 1024
__global__ __launch_bounds__(512) void attn_part(
    const ushort_t* __restrict__ Q, const ushort_t* __restrict__ K,
    const ushort_t* __restrict__ Vt, const ushort_t* __restrict__ mask,
    ushort_t* __restrict__ o0, ushort_t* __restrict__ o1,
    float* __restrict__ lpart) {
    const int tid = threadIdx.x;
    const int lane = tid & 63, wv = tid >> 6;
    const int quad = lane >> 4, l15 = lane & 15;
    const int bh = blockIdx.x;
    const int b = bh >> 4;
    const int zz = blockIdx.z;
    const int kb0 = zz * KHALF;
    const int q0 = blockIdx.y * 128 + wv * 16;

    const ushort_t* Qh = Q + (size_t)bh * Ss * HD;
    const ushort_t* Kh = K + (size_t)bh * Ss * HD;
    const ushort_t* Vh = Vt + (size_t)bh * HD * Ss;
    ushort_t* opart = (zz == 0) ? o0 : o1;

    __shared__ __align__(16) ushort_t Ks[2][64 * 64];  // 16KB
    __shared__ __align__(16) ushort_t Vs[2][64 * 64];  // 16KB
    __shared__ __align__(16) float maskF[KHALF];       // 4KB: (m-4)*log2e
    __shared__ __align__(16) ushort_t Pl[8][16 * STR]; // 9KB
    ushort_t* Pw = &Pl[wv][0];

    for (int i = tid; i < KHALF; i += 512)
        maskF[i] = (bf2f(mask[b * Ss + kb0 + i]) - 4.0f) * 1.4426950f;

    const int r8 = lane >> 3, c8 = lane & 7, gc = c8 ^ r8;  // XOR swizzle
    const int sw = l15 & 7;

    gload_lds16(&Kh[(size_t)(kb0 + wv * 8 + r8) * HD + gc * 8], &Ks[0][wv * 512]);
    gload_lds16(&Vh[(size_t)(wv * 8 + r8) * Ss + kb0 + gc * 8], &Vs[0][wv * 512]);

    bf16x8 qf[2];
    qf[0] = *(const bf16x8*)(&Qh[(size_t)(q0 + l15) * HD + quad * 8]);
    qf[1] = *(const bf16x8*)(&Qh[(size_t)(q0 + l15) * HD + 32 + quad * 8]);

    bf16x8 onesf;
    {
        union { ushort_t u[8]; bf16x8 v; } ou;
        for (int i = 0; i < 8; i++) ou.u[i] = 0x3F80;  // bf16 1.0
        onesf = ou.v;
    }

    const f32x4 fzero = {0.f, 0.f, 0.f, 0.f};
    f32x4 o[4];
    for (int dt = 0; dt < 4; dt++) o[dt] = fzero;
    f32x4 o_l = fzero;

    for (int kk = 0; kk < KHALF; kk += 64) {
        const int kb = kb0 + kk;
        const int buf = (kk >> 6) & 1;
        __syncthreads();

        if (kk + 64 < KHALF) {
            gload_lds16(&Kh[(size_t)(kb + 64 + wv * 8 + r8) * HD + gc * 8],
                        &Ks[buf ^ 1][wv * 512]);
            gload_lds16(&Vh[(size_t)(wv * 8 + r8) * Ss + kb + 64 + gc * 8],
                        &Vs[buf ^ 1][wv * 512]);
        }

        const ushort_t* ks = &Ks[buf][0];
        const ushort_t* vs = &Vs[buf][0];

        f32x4 st[4];
        for (int kt = 0; kt < 4; kt++) {
            f32x4 mk = *(const f32x4*)(&maskF[kk + kt * 16 + quad * 4]);
            bf16x8 kf0 = *(const bf16x8*)(&ks[(kt * 16 + l15) * 64 + ((quad) ^ sw) * 8]);
            bf16x8 kf1 = *(const bf16x8*)(&ks[(kt * 16 + l15) * 64 + ((quad + 4) ^ sw) * 8]);
            st[kt] = __builtin_amdgcn_mfma_f32_16x16x32_bf16(kf0, qf[0], mk, 0, 0, 0);
            st[kt] = __builtin_amdgcn_mfma_f32_16x16x32_bf16(kf1, qf[1], st[kt], 0, 0, 0);
        }

        for (int kt = 0; kt < 4; kt++) {
            float e0 = EXP2(st[kt][0]);
            float e1 = EXP2(st[kt][1]);
            float e2 = EXP2(st[kt][2]);
            float e3 = EXP2(st[kt][3]);
            uint2 pk;
            pk.x = __builtin_amdgcn_perm(fbits(e1), fbits(e0), 0x07060302u);
            pk.y = __builtin_amdgcn_perm(fbits(e3), fbits(e2), 0x07060302u);
            *(uint2*)(&Pw[l15 * STR + kt * 16 + quad * 4]) = pk;
        }

        for (int c = 0; c < 2; c++) {
            union { uint2 u2[2]; bf16x8 v; } pu;
            pu.u2[0] = *(const uint2*)(&Pw[l15 * STR + c * 32 + quad * 8]);
            pu.u2[1] = *(const uint2*)(&Pw[l15 * STR + c * 32 + quad * 8 + 4]);
            bf16x8 pf = pu.v;
            for (int dt = 0; dt < 4; dt++) {
                bf16x8 vf = *(const bf16x8*)(
                    &vs[(dt * 16 + l15) * 64 + ((c * 4 + quad) ^ sw) * 8]);
                o[dt] = __builtin_amdgcn_mfma_f32_16x16x32_bf16(pf, vf, o[dt], 0, 0, 0);
            }
            o_l = __builtin_amdgcn_mfma_f32_16x16x32_bf16(pf, onesf, o_l, 0, 0, 0);
        }
    }

    // write un-normalized partials; layout opart[bh][q][d] (contig 128B rows)
    for (int r = 0; r < 4; r++) {
        int q = q0 + quad * 4 + r;
        for (int dt = 0; dt < 4; dt++) {
            opart[((size_t)bh * Ss + q) * HD + dt * 16 + l15] = f2bf(o[dt][r]);
        }
    }
    if (l15 == 0) {
        for (int r = 0; r < 4; r++) {
            int q = q0 + quad * 4 + r;
            lpart[(size_t)zz * 65536 + bh * Ss + q] = o_l[r];
        }
    }
}

// ---------------------------------------------------------------------------
// Kernel 2b: combine halves: ctx = (o0+o1)/(l0+l1), in place over o0,
// rewritten to [B,S,H*HD] layout for gemm_out. grid=(32,16), 256 thr.
// ---------------------------------------------------------------------------
__global__ __launch_bounds__(256) void combine_k(
    const ushort_t* __restrict__ o0, const ushort_t* __restrict__ o1,
    const float* __restrict__ lpart, ushort_t* __restrict__ ctx) {
    const int bh = blockIdx.x, h = bh & 15, b = bh >> 4;
    const int tid = threadIdx.x;
    const int ql = tid >> 1, dh = (tid & 1) * 32;
    const int q = blockIdx.y * 128 + ql;

    const size_t base = ((size_t)bh * Ss + q) * HD + dh;
    float l0 = lpart[(size_t)bh * Ss + q];
    float l1 = lpart[65536ull + bh * Ss + q];
    float linv = 1.f / (l0 + l1);

    const uint4* p0 = (const uint4*)(o0 + base);
    const uint4* p1 = (const uint4*)(o1 + base);
    // output: ctx[b][s=q][h*64 + dh .. +31]
    uint4* pd = (uint4*)(ctx + ((size_t)(b * Ss + q)) * Dd + h * HD + dh);
    for (int j = 0; j < 4; j++) {
        union { uint4 q4; ushort_t u[8]; } a, c, r;
        a.q4 = p0[j];
        c.q4 = p1[j];
        for (int i = 0; i < 8; i++)
            r.u[i] = f2bf((bf2f(a.u[i]) + bf2f(c.u[i])) * linv);
        pd[j] = r.q4;
    }
}

// ---------------------------------------------------------------------------
// Kernel 3: output projection + bias + residual -> bf16 x buffer.
// 64x128 tiles, grid=(8,64)=512 blocks; double-buffered staging.
// ---------------------------------------------------------------------------
__global__ __launch_bounds__(256) void gemm_out(
    const ushort_t* __restrict__ A, const ushort_t* __restrict__ Wt,
    const ushort_t* __restrict__ bo, const ushort_t* __restrict__ X,
    ushort_t* __restrict__ xout) {
    __shared__ __align__(16) ushort_t smem[2][6144];  // 24 KB

    const int tid = threadIdx.x;
    const int lane = tid & 63, wv = tid >> 6;
    const int quad = lane >> 4, l15 = lane & 15;
    const int wrow = (wv >> 1) * 32, wcol = (wv & 1) * 64;
    const int row0 = blockIdx.y * 64, col0 = blockIdx.x * 128;
    const int lrow = lane >> 2, lcol = (lane & 3) * 8;

    const f32x4 fzero = {0.f, 0.f, 0.f, 0.f};
    f32x4 acc[2][4];
    for (int mt = 0; mt < 2; mt++)
        for (int nt = 0; nt < 4; nt++) acc[mt][nt] = fzero;

    gload_lds16(&A[(size_t)(row0 + wv * 16 + lrow) * Dd + lcol], &smem[0][wv * 512]);
    for (int j = 0; j < 2; j++) {
        int ch = wv * 2 + j;
        gload_lds16(&Wt[(size_t)(col0 + ch * 16 + lrow) * Dd + lcol],
                    &smem[0][2048 + ch * 512]);
    }

    for (int k0 = 0; k0 < Dd; k0 += 32) {
        const int buf = (k0 >> 5) & 1;
        __syncthreads();
        if (k0 + 32 < Dd) {
            gload_lds16(&A[(size_t)(row0 + wv * 16 + lrow) * Dd + k0 + 32 + lcol],
                        &smem[buf ^ 1][wv * 512]);
            for (int j = 0; j < 2; j++) {
                int ch = wv * 2 + j;
                gload_lds16(&Wt[(size_t)(col0 + ch * 16 + lrow) * Dd + k0 + 32 + lcol],
                            &smem[buf ^ 1][2048 + ch * 512]);
            }
        }
        const ushort_t* As = &smem[buf][0];
        const ushort_t* Bs = &smem[buf][2048];
        bf16x8 af[2], bfr[4];
        for (int mt = 0; mt < 2; mt++)
            af[mt] = *(const bf16x8*)(&As[(wrow + mt * 16 + l15) * 32 + quad * 8]);
        for (int nt = 0; nt < 4; nt++)
            bfr[nt] = *(const bf16x8*)(&Bs[(wcol + nt * 16 + l15) * 32 + quad * 8]);
        for (int mt = 0; mt < 2; mt++)
            for (int nt = 0; nt < 4; nt++)
                acc[mt][nt] = __builtin_amdgcn_mfma_f32_16x16x32_bf16(
                    af[mt], bfr[nt], acc[mt][nt], 0, 0, 0);
    }

    for (int mt = 0; mt < 2; mt++)
        for (int nt = 0; nt < 4; nt++)
            for (int r = 0; r < 4; r++) {
                int gm = row0 + wrow + mt * 16 + quad * 4 + r;
                int gn = col0 + wcol + nt * 16 + l15;
                float v = acc[mt][nt][r] + bf2f(bo[gn]) + bf2f(X[(size_t)gm * Dd + gn]);
                xout[(size_t)gm * Dd + gn] = f2bf(v);
            }
}

// ---------------------------------------------------------------------------
// Kernel 4: LayerNorm over rows of x (bf16) -> out (dtype per flag).
// ---------------------------------------------------------------------------
__global__ __launch_bounds__(256) void ln_k(
    const ushort_t* __restrict__ x, const ushort_t* __restrict__ gamma,
    const ushort_t* __restrict__ beta, const int* __restrict__ flag,
    void* __restrict__ out) {
    const int row = blockIdx.x;
    const int tid = threadIdx.x;
    const int f = *flag;

    union { uint2 q; ushort_t u[4]; } xv;
    xv.q = ((const uint2*)(x + (size_t)row * Dd))[tid];
    float xi[4];
    for (int i = 0; i < 4; i++) xi[i] = bf2f(xv.u[i]);
    float s = (xi[0] + xi[1]) + (xi[2] + xi[3]);
    float ss = (xi[0] * xi[0] + xi[1] * xi[1]) + (xi[2] * xi[2] + xi[3] * xi[3]);
    for (int off = 1; off < 64; off <<= 1) {
        s += __shfl_xor(s, off);
        ss += __shfl_xor(ss, off);
    }
    __shared__ float ps[4], pss[4];
    int wv = tid >> 6;
    if ((tid & 63) == 0) { ps[wv] = s; pss[wv] = ss; }
    __syncthreads();
    s = ps[0] + ps[1] + ps[2] + ps[3];
    ss = pss[0] + pss[1] + pss[2] + pss[3];
    float mu = s * (1.f / Dd);
    float var = ss * (1.f / Dd) - mu * mu;
    float rstd = rsqrtf(fmaxf(var, 0.f) + 1e-12f);

    const int c0 = tid * 4;
    float r[4];
    for (int i = 0; i < 4; i++) {
        float g = bf2f(gamma[c0 + i]);
        float bb = bf2f(beta[c0 + i]);
        r[i] = (xi[i] - mu) * rstd * g + bb;
    }
    if (f) {
        float4 o4 = {r[0], r[1], r[2], r[3]};
        ((float4*)out)[(size_t)row * 256 + tid] = o4;
    } else {
        union { ushort_t u[4]; uint2 q; } pk;
        for (int i = 0; i < 4; i++) pk.u[i] = f2bf(r[i]);
        *(uint2*)((ushort_t*)out + (size_t)row * Dd + c0) = pk.q;
    }
}

// ---------------------------------------------------------------------------
extern "C" void kernel_launch(void* const* d_in, const int* in_sizes, int n_in,
                              void* d_out, int out_size, void* d_ws, size_t ws_size,
                              hipStream_t stream) {
    char* ws = (char*)d_ws;
    int* flag       = (int*)ws;                          // @0
    ushort_t* cMask = (ushort_t*)(ws + (64ull << 10));   // @64KB  (8KB)
    ushort_t* cB    = (ushort_t*)(ws + (96ull << 10));   // @96KB  (12KB)
    float* lpart    = (float*)(ws + (512ull << 10));     // @512KB (512KB)
    ushort_t* cX    = (ushort_t*)(ws + (1ull << 20));    // @1MB   (8MB)
    ushort_t* o1b   = (ushort_t*)(ws + (9ull << 20));    // @9MB   (8MB) partial half1
    ushort_t* wt    = (ushort_t*)(ws + (17ull << 20));   // @17MB  (8MB)
    ushort_t* Qb    = (ushort_t*)(ws + (25ull << 20));   // @25MB  (8MB)
    ushort_t* Kb    = (ushort_t*)(ws + (33ull << 20));   // @33MB  (8MB)
    ushort_t* Vtb   = (ushort_t*)(ws + (41ull << 20));   // @41MB  (8MB)
    ushort_t* o0b   = (ushort_t*)(ws + (49ull << 20));   // @49MB  (8MB) partial half0
    ushort_t* ctx   = (ushort_t*)(ws + (57ull << 20));   // @57MB  (8MB)
    ushort_t* xbuf  = (ushort_t*)(ws + (25ull << 20));   // reuse Qb (8MB bf16)

    hipLaunchKernelGGL(prep_k, dim3(5120), dim3(256), 0, stream,
                       d_in[0], d_in[1], d_in[3], d_in[5], d_in[7], d_in[9],
                       d_in[10], d_in[11], d_in[2], d_in[4], d_in[6], d_in[8],
                       flag, cX, cMask, cB, wt);
    hipLaunchKernelGGL(gemm_qkv, dim3(8, 32, 3), dim3(256), 0, stream,
                       cX, wt, cB, Qb, Kb, Vtb);
    hipLaunchKernelGGL(attn_part, dim3(32, 16, 2), dim3(512), 0, stream,
                       Qb, Kb, Vtb, cMask, o0b, o1b, lpart);
    hipLaunchKernelGGL(combine_k, dim3(32, 16), dim3(256), 0, stream,
                       o0b, o1b, lpart, ctx);
    hipLaunchKernelGGL(gemm_out, dim3(8, 64), dim3(256), 0, stream,
                       ctx, wt + 3ull * Dd * Dd, cB + 3 * 1024, cX, xbuf);
    hipLaunchKernelGGL(ln_k, dim3(Mtot), dim3(256), 0, stream,
                       xbuf, cB + 4 * 1024, cB + 5 * 1024, flag, d_out);
}

// Round 11
// 216.582 us; speedup vs baseline: 1.0426x; 1.0426x over previous
//
#include <hip/hip_runtime.h>
#include <stdint.h>

// Problem: B=2, S=2048, D=1024, H=16, HD=64.
// Reference dtype fp32; harness may deliver fp32 OR bf16. Runtime-detected.
#define Bb 2
#define Ss 2048
#define Dd 1024
#define Hh 16
#define HD 64
#define Mtot 4096  // B*S

typedef __bf16 bf16x8 __attribute__((ext_vector_type(8)));
typedef float f32x4 __attribute__((ext_vector_type(4)));
typedef unsigned short ushort_t;

#if __has_builtin(__builtin_amdgcn_exp2f)
#define EXP2(x) __builtin_amdgcn_exp2f(x)   // single v_exp_f32
#else
#define EXP2(x) __expf((x) * 0.6931472f)
#endif

__device__ __forceinline__ float bf2f(ushort_t u) {
    union { uint32_t i; float f; } v;
    v.i = ((uint32_t)u) << 16;
    return v.f;
}

__device__ __forceinline__ ushort_t f2bf(float f) {
    union { float f; uint32_t i; } v;
    v.f = f;
    uint32_t u = v.i;
    u += 0x7FFFu + ((u >> 16) & 1u);  // round-to-nearest-even
    return (ushort_t)(u >> 16);
}

__device__ __forceinline__ uint32_t fbits(float f) {
    union { float f; uint32_t i; } v; v.f = f; return v.i;
}

__device__ __forceinline__ float load_in(const void* p, size_t i, int isf32) {
    if (isf32) return ((const float*)p)[i];
    return bf2f(((const ushort_t*)p)[i]);
}

// async global->LDS, 16B per lane; LDS dest = wave-uniform base + lane*16 (HW)
__device__ __forceinline__ void gload_lds16(const void* g, void* l) {
    __builtin_amdgcn_global_load_lds(
        (const __attribute__((address_space(1))) void*)g,
        (__attribute__((address_space(3))) void*)l, 16, 0, 0);
}

// ---------------------------------------------------------------------------
// Kernel P: fused prep. Blocks 0..1023: VECTORIZED convert of X/mask/biases
// (8 elems per task: float4 x2 -> packed uint4, or uint4 passthrough).
// Blocks 1024..5119: transpose+convert weights W[K][N] -> wt[N][K].
// Every block self-detects input dtype from X's first 2048 ushorts.
// ---------------------------------------------------------------------------
#define NVEC 525568ull  // 524288 (X) + 512 (mask) + 768 (6x1024 biases)
__global__ __launch_bounds__(256) void prep_k(
    const void* X, const void* mask, const void* bq, const void* bk,
    const void* bv, const void* bo, const void* g, const void* be,
    const void* Wq, const void* Wk, const void* Wv, const void* Wo,
    int* __restrict__ flag, ushort_t* __restrict__ cX,
    ushort_t* __restrict__ cMask, ushort_t* __restrict__ cB,
    ushort_t* __restrict__ wt) {
    __shared__ int sflag;
    __shared__ ushort_t tile[32][33];
    const int tid = threadIdx.x;
    {
        const int lane = tid & 63;
        if (tid < 64) {
            const ushort_t* Xu = (const ushort_t*)X;
            int local = 0;
            for (int i = lane; i < 2048; i += 64) {
                int e = (Xu[i] >> 7) & 0xFF;
                local += (e >= 0x90);
            }
            for (int off = 1; off < 64; off <<= 1) local += __shfl_xor(local, off);
            if (lane == 0) sflag = (local >= 4) ? 1 : 0;
        }
    }
    __syncthreads();
    const int f = sflag;
    if (blockIdx.x == 0 && tid == 0) *flag = f;

    if (blockIdx.x < 1024) {
        const size_t stride = 1024ull * 256ull;
        for (size_t t = (size_t)blockIdx.x * 256 + tid; t < NVEC; t += stride) {
            const void* src;
            ushort_t* dst;
            size_t v;
            if (t < 524288ull) {
                src = X; dst = cX; v = t;
            } else if (t < 524800ull) {
                src = mask; dst = cMask; v = t - 524288ull;
            } else {
                size_t j = t - 524800ull;        // 0..767, 128 vecs / segment
                int w = (int)(j >> 7);
                src = (w == 0) ? bq : (w == 1) ? bk : (w == 2) ? bv
                    : (w == 3) ? bo : (w == 4) ? g : be;
                dst = cB + w * 1024;
                v = j & 127;
            }
            if (f) {
                const float4* s4 = (const float4*)src;
                float4 a = s4[v * 2], b = s4[v * 2 + 1];
                union { ushort_t u[8]; uint4 q; } pk;
                pk.u[0] = f2bf(a.x); pk.u[1] = f2bf(a.y);
                pk.u[2] = f2bf(a.z); pk.u[3] = f2bf(a.w);
                pk.u[4] = f2bf(b.x); pk.u[5] = f2bf(b.y);
                pk.u[6] = f2bf(b.z); pk.u[7] = f2bf(b.w);
                ((uint4*)dst)[v] = pk.q;
            } else {
                ((uint4*)dst)[v] = ((const uint4*)src)[v];
            }
        }
    } else {
        int id2 = blockIdx.x - 1024;
        int z = id2 >> 10;
        int rem = id2 & 1023;
        int bx = rem & 31, by = rem >> 5;
        const void* W = (z == 0) ? Wq : (z == 1) ? Wk : (z == 2) ? Wv : Wo;
        ushort_t* T = wt + (size_t)z * Dd * Dd;
        int tx = tid & 31, ty = tid >> 5;
        int x = bx * 32 + tx;
        int y0 = by * 32;
        for (int i = 0; i < 4; i++) {
            int y = y0 + ty + i * 8;
            tile[ty + i * 8][tx] = f2bf(load_in(W, (size_t)y * Dd + x, f));
        }
        __syncthreads();
        int x2 = by * 32 + tx;
        int y20 = bx * 32;
        for (int i = 0; i < 4; i++) {
            int y = y20 + ty + i * 8;
            T[(size_t)y * Dd + x2] = tile[tx][ty + i * 8];
        }
    }
}

// ---------------------------------------------------------------------------
// Kernel 1: fused QKV projection. grid=(N/128, M/128, 3), block=256 (4 waves)
// Double-buffered global_load_lds(16B) staging. Q pre-scaled by 0.125*log2e.
// Epilogue: Q/K direct register stores; V^T via LDS transpose (2B x 4KB-
// stride scatter is real there). Q,K: [B,H,S,HD]; V^T: [B,H,HD,S].
// ---------------------------------------------------------------------------
__global__ __launch_bounds__(256) void gemm_qkv(
    const ushort_t* __restrict__ X, const ushort_t* __restrict__ wt,
    const ushort_t* __restrict__ cB,
    ushort_t* __restrict__ Qb, ushort_t* __restrict__ Kb, ushort_t* __restrict__ Vtb) {
    const int z = blockIdx.z;
    const ushort_t* Wt = wt + (size_t)z * Dd * Dd;
    const ushort_t* bias = cB + z * 1024;

    __shared__ __align__(16) ushort_t smem[2][2][128 * 32];  // 32 KB

    const int tid = threadIdx.x;
    const int lane = tid & 63, wv = tid >> 6;
    const int quad = lane >> 4, l15 = lane & 15;
    const int wrow = (wv >> 1) * 64, wcol = (wv & 1) * 64;
    const int row0 = blockIdx.y * 128, col0 = blockIdx.x * 128;
    const int lrow = lane >> 2, lcol = (lane & 3) * 8;

    const f32x4 fzero = {0.f, 0.f, 0.f, 0.f};
    f32x4 acc[4][4];
    for (int mt = 0; mt < 4; mt++)
        for (int nt = 0; nt < 4; nt++) acc[mt][nt] = fzero;

    for (int j = 0; j < 2; j++) {
        int ch = wv * 2 + j;
        gload_lds16(&X[(size_t)(row0 + ch * 16 + lrow) * Dd + lcol],
                    &smem[0][0][ch * 512]);
        gload_lds16(&Wt[(size_t)(col0 + ch * 16 + lrow) * Dd + lcol],
                    &smem[0][1][ch * 512]);
    }

    for (int k0 = 0; k0 < Dd; k0 += 32) {
        const int buf = (k0 >> 5) & 1;
        __syncthreads();
        if (k0 + 32 < Dd) {
            for (int j = 0; j < 2; j++) {
                int ch = wv * 2 + j;
                gload_lds16(&X[(size_t)(row0 + ch * 16 + lrow) * Dd + k0 + 32 + lcol],
                            &smem[buf ^ 1][0][ch * 512]);
                gload_lds16(&Wt[(size_t)(col0 + ch * 16 + lrow) * Dd + k0 + 32 + lcol],
                            &smem[buf ^ 1][1][ch * 512]);
            }
        }
        const ushort_t* As = &smem[buf][0][0];
        const ushort_t* Bs = &smem[buf][1][0];
        bf16x8 af[4], bfr[4];
        for (int mt = 0; mt < 4; mt++)
            af[mt] = *(const bf16x8*)(&As[(wrow + mt * 16 + l15) * 32 + quad * 8]);
        for (int nt = 0; nt < 4; nt++)
            bfr[nt] = *(const bf16x8*)(&Bs[(wcol + nt * 16 + l15) * 32 + quad * 8]);
        for (int mt = 0; mt < 4; mt++)
            for (int nt = 0; nt < 4; nt++)
                acc[mt][nt] = __builtin_amdgcn_mfma_f32_16x16x32_bf16(
                    af[mt], bfr[nt], acc[mt][nt], 0, 0, 0);
    }

    const float qscale = 0.18033688f;  // 0.125 * log2(e)
    if (z != 2) {
        ushort_t* Ob = (z == 0) ? Qb : Kb;
        for (int mt = 0; mt < 4; mt++)
            for (int nt = 0; nt < 4; nt++) {
                int gn = col0 + wcol + nt * 16 + l15;
                int h = gn >> 6, d = gn & 63;
                float bv_ = bf2f(bias[gn]);
                for (int r = 0; r < 4; r++) {
                    int gm = row0 + wrow + mt * 16 + quad * 4 + r;
                    float v = acc[mt][nt][r] + bv_;
                    if (z == 0) v *= qscale;
                    int b = gm >> 11, s = gm & 2047;
                    Ob[((size_t)((b * Hh + h) * Ss + s)) * HD + d] = f2bf(v);
                }
            }
    } else {
        ushort_t* Cs = &smem[0][0][0];
        for (int mt = 0; mt < 4; mt++) {
            __syncthreads();
            for (int nt = 0; nt < 4; nt++) {
                int gn = col0 + wcol + nt * 16 + l15;
                float bv_ = bf2f(bias[gn]);
                for (int r = 0; r < 4; r++) {
                    float v = acc[mt][nt][r] + bv_;
                    int ric = (wv >> 1) * 16 + quad * 4 + r;
                    Cs[ric * 136 + wcol + nt * 16 + l15] = f2bf(v);
                }
            }
            __syncthreads();
            int c = tid >> 1, r0 = (tid & 1) * 16;
            int gn = col0 + c, h = gn >> 6, d = gn & 63;
            int gmbase = row0 + (r0 >> 4) * 64 + mt * 16;
            int b = gmbase >> 11, s0 = gmbase & 2047;
            union { ushort_t u[16]; uint4 q[2]; } pk;
            for (int i = 0; i < 16; i++) pk.u[i] = Cs[(r0 + i) * 136 + c];
            uint4* dst = (uint4*)&Vtb[((size_t)((b * Hh + h) * HD + d)) * Ss + s0];
            dst[0] = pk.q[0];
            dst[1] = pk.q[1];
        }
    }
}

// ---------------------------------------------------------------------------
// Kernel 2: flash attention (R8 config — best measured). S^T orientation,
// streaming softmax (fixed shift in mask, cancelled by norm), mask as MFMA C
// operand, l via ones-column PV MFMA. grid=(B*H, S/128), block=512.
// ---------------------------------------------------------------------------
#define STR 76
__global__ __launch_bounds__(512) void attn(
    const ushort_t* __restrict__ Q, const ushort_t* __restrict__ K,
    const ushort_t* __restrict__ Vt, const ushort_t* __restrict__ mask,
    ushort_t* __restrict__ ctx) {
    const int tid = threadIdx.x;
    const int lane = tid & 63, wv = tid >> 6;
    const int quad = lane >> 4, l15 = lane & 15;
    const int bh = blockIdx.x;
    const int b = bh >> 4, h = bh & 15;
    const int q0 = blockIdx.y * 128 + wv * 16;

    const ushort_t* Qh = Q + (size_t)bh * Ss * HD;
    const ushort_t* Kh = K + (size_t)bh * Ss * HD;
    const ushort_t* Vh = Vt + (size_t)bh * HD * Ss;

    __shared__ __align__(16) ushort_t Ks[2][64 * 64];  // 16KB
    __shared__ __align__(16) ushort_t Vs[2][64 * 64];  // 16KB
    __shared__ __align__(16) float maskF[Ss];          // 8KB: (m-4)*log2e
    __shared__ __align__(16) ushort_t Pl[8][16 * STR]; // 19KB
    ushort_t* Pw = &Pl[wv][0];

    for (int i = tid; i < Ss; i += 512)
        maskF[i] = (bf2f(mask[b * Ss + i]) - 4.0f) * 1.4426950f;

    const int r8 = lane >> 3, c8 = lane & 7, gc = c8 ^ r8;  // XOR swizzle
    const int sw = l15 & 7;

    gload_lds16(&Kh[(size_t)(wv * 8 + r8) * HD + gc * 8], &Ks[0][wv * 512]);
    gload_lds16(&Vh[(size_t)(wv * 8 + r8) * Ss + gc * 8], &Vs[0][wv * 512]);

    bf16x8 qf[2];
    qf[0] = *(const bf16x8*)(&Qh[(size_t)(q0 + l15) * HD + quad * 8]);
    qf[1] = *(const bf16x8*)(&Qh[(size_t)(q0 + l15) * HD + 32 + quad * 8]);

    bf16x8 onesf;
    {
        union { ushort_t u[8]; bf16x8 v; } ou;
        for (int i = 0; i < 8; i++) ou.u[i] = 0x3F80;  // bf16 1.0
        onesf = ou.v;
    }

    const f32x4 fzero = {0.f, 0.f, 0.f, 0.f};
    f32x4 o[4];
    for (int dt = 0; dt < 4; dt++) o[dt] = fzero;
    f32x4 o_l = fzero;  // per-query sum of P (C-layout)

    for (int kb = 0; kb < Ss; kb += 64) {
        const int buf = (kb >> 6) & 1;
        __syncthreads();

        if (kb + 64 < Ss) {
            gload_lds16(&Kh[(size_t)(kb + 64 + wv * 8 + r8) * HD + gc * 8],
                        &Ks[buf ^ 1][wv * 512]);
            gload_lds16(&Vh[(size_t)(wv * 8 + r8) * Ss + kb + 64 + gc * 8],
                        &Vs[buf ^ 1][wv * 512]);
        }

        const ushort_t* ks = &Ks[buf][0];
        const ushort_t* vs = &Vs[buf][0];

        f32x4 st[4];
        for (int kt = 0; kt < 4; kt++) {
            f32x4 mk = *(const f32x4*)(&maskF[kb + kt * 16 + quad * 4]);
            bf16x8 kf0 = *(const bf16x8*)(&ks[(kt * 16 + l15) * 64 + ((quad) ^ sw) * 8]);
            bf16x8 kf1 = *(const bf16x8*)(&ks[(kt * 16 + l15) * 64 + ((quad + 4) ^ sw) * 8]);
            st[kt] = __builtin_amdgcn_mfma_f32_16x16x32_bf16(kf0, qf[0], mk, 0, 0, 0);
            st[kt] = __builtin_amdgcn_mfma_f32_16x16x32_bf16(kf1, qf[1], st[kt], 0, 0, 0);
        }

        for (int kt = 0; kt < 4; kt++) {
            float e0 = EXP2(st[kt][0]);
            float e1 = EXP2(st[kt][1]);
            float e2 = EXP2(st[kt][2]);
            float e3 = EXP2(st[kt][3]);
            uint2 pk;
            pk.x = __builtin_amdgcn_perm(fbits(e1), fbits(e0), 0x07060302u);
            pk.y = __builtin_amdgcn_perm(fbits(e3), fbits(e2), 0x07060302u);
            *(uint2*)(&Pw[l15 * STR + kt * 16 + quad * 4]) = pk;
        }

        for (int c = 0; c < 2; c++) {
            union { uint2 u2[2]; bf16x8 v; } pu;
            pu.u2[0] = *(const uint2*)(&Pw[l15 * STR + c * 32 + quad * 8]);
            pu.u2[1] = *(const uint2*)(&Pw[l15 * STR + c * 32 + quad * 8 + 4]);
            bf16x8 pf = pu.v;
            for (int dt = 0; dt < 4; dt++) {
                bf16x8 vf = *(const bf16x8*)(
                    &vs[(dt * 16 + l15) * 64 + ((c * 4 + quad) ^ sw) * 8]);
                o[dt] = __builtin_amdgcn_mfma_f32_16x16x32_bf16(pf, vf, o[dt], 0, 0, 0);
            }
            o_l = __builtin_amdgcn_mfma_f32_16x16x32_bf16(pf, onesf, o_l, 0, 0, 0);
        }
    }

    for (int r = 0; r < 4; r++) {
        int q = q0 + quad * 4 + r;
        float linv = 1.f / o_l[r];
        for (int dt = 0; dt < 4; dt++) {
            ctx[((size_t)(b * Ss + q)) * Dd + h * HD + dt * 16 + l15] =
                f2bf(o[dt][r] * linv);
        }
    }
}

// ---------------------------------------------------------------------------
// Kernel 3: output projection + bias + residual -> bf16 x buffer.
// 64x128 tiles, grid=(8,64)=512 blocks; double-buffered staging.
// ---------------------------------------------------------------------------
__global__ __launch_bounds__(256) void gemm_out(
    const ushort_t* __restrict__ A, const ushort_t* __restrict__ Wt,
    const ushort_t* __restrict__ bo, const ushort_t* __restrict__ X,
    ushort_t* __restrict__ xout) {
    __shared__ __align__(16) ushort_t smem[2][6144];  // 24 KB

    const int tid = threadIdx.x;
    const int lane = tid & 63, wv = tid >> 6;
    const int quad = lane >> 4, l15 = lane & 15;
    const int wrow = (wv >> 1) * 32, wcol = (wv & 1) * 64;
    const int row0 = blockIdx.y * 64, col0 = blockIdx.x * 128;
    const int lrow = lane >> 2, lcol = (lane & 3) * 8;

    const f32x4 fzero = {0.f, 0.f, 0.f, 0.f};
    f32x4 acc[2][4];
    for (int mt = 0; mt < 2; mt++)
        for (int nt = 0; nt < 4; nt++) acc[mt][nt] = fzero;

    gload_lds16(&A[(size_t)(row0 + wv * 16 + lrow) * Dd + lcol], &smem[0][wv * 512]);
    for (int j = 0; j < 2; j++) {
        int ch = wv * 2 + j;
        gload_lds16(&Wt[(size_t)(col0 + ch * 16 + lrow) * Dd + lcol],
                    &smem[0][2048 + ch * 512]);
    }

    for (int k0 = 0; k0 < Dd; k0 += 32) {
        const int buf = (k0 >> 5) & 1;
        __syncthreads();
        if (k0 + 32 < Dd) {
            gload_lds16(&A[(size_t)(row0 + wv * 16 + lrow) * Dd + k0 + 32 + lcol],
                        &smem[buf ^ 1][wv * 512]);
            for (int j = 0; j < 2; j++) {
                int ch = wv * 2 + j;
                gload_lds16(&Wt[(size_t)(col0 + ch * 16 + lrow) * Dd + k0 + 32 + lcol],
                            &smem[buf ^ 1][2048 + ch * 512]);
            }
        }
        const ushort_t* As = &smem[buf][0];
        const ushort_t* Bs = &smem[buf][2048];
        bf16x8 af[2], bfr[4];
        for (int mt = 0; mt < 2; mt++)
            af[mt] = *(const bf16x8*)(&As[(wrow + mt * 16 + l15) * 32 + quad * 8]);
        for (int nt = 0; nt < 4; nt++)
            bfr[nt] = *(const bf16x8*)(&Bs[(wcol + nt * 16 + l15) * 32 + quad * 8]);
        for (int mt = 0; mt < 2; mt++)
            for (int nt = 0; nt < 4; nt++)
                acc[mt][nt] = __builtin_amdgcn_mfma_f32_16x16x32_bf16(
                    af[mt], bfr[nt], acc[mt][nt], 0, 0, 0);
    }

    for (int mt = 0; mt < 2; mt++)
        for (int nt = 0; nt < 4; nt++)
            for (int r = 0; r < 4; r++) {
                int gm = row0 + wrow + mt * 16 + quad * 4 + r;
                int gn = col0 + wcol + nt * 16 + l15;
                float v = acc[mt][nt][r] + bf2f(bo[gn]) + bf2f(X[(size_t)gm * Dd + gn]);
                xout[(size_t)gm * Dd + gn] = f2bf(v);
            }
}

// ---------------------------------------------------------------------------
// Kernel 4: LayerNorm over rows of x (bf16) -> out (dtype per flag).
// ---------------------------------------------------------------------------
__global__ __launch_bounds__(256) void ln_k(
    const ushort_t* __restrict__ x, const ushort_t* __restrict__ gamma,
    const ushort_t* __restrict__ beta, const int* __restrict__ flag,
    void* __restrict__ out) {
    const int row = blockIdx.x;
    const int tid = threadIdx.x;
    const int f = *flag;

    union { uint2 q; ushort_t u[4]; } xv;
    xv.q = ((const uint2*)(x + (size_t)row * Dd))[tid];
    float xi[4];
    for (int i = 0; i < 4; i++) xi[i] = bf2f(xv.u[i]);
    float s = (xi[0] + xi[1]) + (xi[2] + xi[3]);
    float ss = (xi[0] * xi[0] + xi[1] * xi[1]) + (xi[2] * xi[2] + xi[3] * xi[3]);
    for (int off = 1; off < 64; off <<= 1) {
        s += __shfl_xor(s, off);
        ss += __shfl_xor(ss, off);
    }
    __shared__ float ps[4], pss[4];
    int wv = tid >> 6;
    if ((tid & 63) == 0) { ps[wv] = s; pss[wv] = ss; }
    __syncthreads();
    s = ps[0] + ps[1] + ps[2] + ps[3];
    ss = pss[0] + pss[1] + pss[2] + pss[3];
    float mu = s * (1.f / Dd);
    float var = ss * (1.f / Dd) - mu * mu;
    float rstd = rsqrtf(fmaxf(var, 0.f) + 1e-12f);

    const int c0 = tid * 4;
    float r[4];
    for (int i = 0; i < 4; i++) {
        float g = bf2f(gamma[c0 + i]);
        float bb = bf2f(beta[c0 + i]);
        r[i] = (xi[i] - mu) * rstd * g + bb;
    }
    if (f) {
        float4 o4 = {r[0], r[1], r[2], r[3]};
        ((float4*)out)[(size_t)row * 256 + tid] = o4;
    } else {
        union { ushort_t u[4]; uint2 q; } pk;
        for (int i = 0; i < 4; i++) pk.u[i] = f2bf(r[i]);
        *(uint2*)((ushort_t*)out + (size_t)row * Dd + c0) = pk.q;
    }
}

// ---------------------------------------------------------------------------
extern "C" void kernel_launch(void* const* d_in, const int* in_sizes, int n_in,
                              void* d_out, int out_size, void* d_ws, size_t ws_size,
                              hipStream_t stream) {
    char* ws = (char*)d_ws;
    int* flag       = (int*)ws;                          // @0
    ushort_t* cMask = (ushort_t*)(ws + (64ull << 10));   // @64KB  (8KB)
    ushort_t* cB    = (ushort_t*)(ws + (96ull << 10));   // @96KB  (12KB)
    ushort_t* cX    = (ushort_t*)(ws + (1ull << 20));    // @1MB   (8MB)
    ushort_t* wt    = (ushort_t*)(ws + (17ull << 20));   // @17MB  (8MB)
    ushort_t* Qb    = (ushort_t*)(ws + (25ull << 20));   // @25MB  (8MB)
    ushort_t* Kb    = (ushort_t*)(ws + (33ull << 20));   // @33MB  (8MB)
    ushort_t* Vtb   = (ushort_t*)(ws + (41ull << 20));   // @41MB  (8MB)
    ushort_t* ctx   = (ushort_t*)(ws + (49ull << 20));   // @49MB  (8MB)
    ushort_t* xbuf  = (ushort_t*)(ws + (25ull << 20));   // reuse Qb (8MB bf16)

    hipLaunchKernelGGL(prep_k, dim3(5120), dim3(256), 0, stream,
                       d_in[0], d_in[1], d_in[3], d_in[5], d_in[7], d_in[9],
                       d_in[10], d_in[11], d_in[2], d_in[4], d_in[6], d_in[8],
                       flag, cX, cMask, cB, wt);
    hipLaunchKernelGGL(gemm_qkv, dim3(8, 32, 3), dim3(256), 0, stream,
                       cX, wt, cB, Qb, Kb, Vtb);
    hipLaunchKernelGGL(attn, dim3(32, 16), dim3(512), 0, stream,
                       Qb, Kb, Vtb, cMask, ctx);
    hipLaunchKernelGGL(gemm_out, dim3(8, 64), dim3(256), 0, stream,
                       ctx, wt + 3ull * Dd * Dd, cB + 3 * 1024, cX, xbuf);
    hipLaunchKernelGGL(ln_k, dim3(Mtot), dim3(256), 0, stream,
                       xbuf, cB + 4 * 1024, cB + 5 * 1024, flag, d_out);
}

// Round 12
// 205.759 us; speedup vs baseline: 1.0974x; 1.0526x over previous
//
#include <hip/hip_runtime.h>
#include <stdint.h>

// Problem: B=2, S=2048, D=1024, H=16, HD=64.
// Reference dtype fp32; harness may deliver fp32 OR bf16. Runtime-detected.
#define Bb 2
#define Ss 2048
#define Dd 1024
#define Hh 16
#define HD 64
#define Mtot 4096  // B*S

typedef __bf16 bf16x8 __attribute__((ext_vector_type(8)));
typedef float f32x4 __attribute__((ext_vector_type(4)));
typedef unsigned short ushort_t;

#if __has_builtin(__builtin_amdgcn_exp2f)
#define EXP2(x) __builtin_amdgcn_exp2f(x)   // single v_exp_f32
#else
#define EXP2(x) __expf((x) * 0.6931472f)
#endif

__device__ __forceinline__ float bf2f(ushort_t u) {
    union { uint32_t i; float f; } v;
    v.i = ((uint32_t)u) << 16;
    return v.f;
}

__device__ __forceinline__ ushort_t f2bf(float f) {
    union { float f; uint32_t i; } v;
    v.f = f;
    uint32_t u = v.i;
    u += 0x7FFFu + ((u >> 16) & 1u);  // round-to-nearest-even
    return (ushort_t)(u >> 16);
}

__device__ __forceinline__ uint32_t fbits(float f) {
    union { float f; uint32_t i; } v; v.f = f; return v.i;
}

__device__ __forceinline__ float load_in(const void* p, size_t i, int isf32) {
    if (isf32) return ((const float*)p)[i];
    return bf2f(((const ushort_t*)p)[i]);
}

// async global->LDS, 16B per lane; LDS dest = wave-uniform base + lane*16 (HW)
__device__ __forceinline__ void gload_lds16(const void* g, void* l) {
    __builtin_amdgcn_global_load_lds(
        (const __attribute__((address_space(1))) void*)g,
        (__attribute__((address_space(3))) void*)l, 16, 0, 0);
}

// ---------------------------------------------------------------------------
// Kernel P: fused prep. Blocks 0..1023: VECTORIZED convert of X/mask/biases
// (8 elems per task: float4 x2 -> packed uint4, or uint4 passthrough).
// Blocks 1024..5119: transpose+convert weights W[K][N] -> wt[N][K].
// Every block self-detects input dtype from X's first 2048 ushorts.
// ---------------------------------------------------------------------------
#define NVEC 525568ull  // 524288 (X) + 512 (mask) + 768 (6x1024 biases)
__global__ __launch_bounds__(256) void prep_k(
    const void* X, const void* mask, const void* bq, const void* bk,
    const void* bv, const void* bo, const void* g, const void* be,
    const void* Wq, const void* Wk, const void* Wv, const void* Wo,
    int* __restrict__ flag, ushort_t* __restrict__ cX,
    ushort_t* __restrict__ cMask, ushort_t* __restrict__ cB,
    ushort_t* __restrict__ wt) {
    __shared__ int sflag;
    __shared__ ushort_t tile[32][33];
    const int tid = threadIdx.x;
    {
        const int lane = tid & 63;
        if (tid < 64) {
            const ushort_t* Xu = (const ushort_t*)X;
            int local = 0;
            for (int i = lane; i < 2048; i += 64) {
                int e = (Xu[i] >> 7) & 0xFF;
                local += (e >= 0x90);
            }
            for (int off = 1; off < 64; off <<= 1) local += __shfl_xor(local, off);
            if (lane == 0) sflag = (local >= 4) ? 1 : 0;
        }
    }
    __syncthreads();
    const int f = sflag;
    if (blockIdx.x == 0 && tid == 0) *flag = f;

    if (blockIdx.x < 1024) {
        const size_t stride = 1024ull * 256ull;
        for (size_t t = (size_t)blockIdx.x * 256 + tid; t < NVEC; t += stride) {
            const void* src;
            ushort_t* dst;
            size_t v;
            if (t < 524288ull) {
                src = X; dst = cX; v = t;
            } else if (t < 524800ull) {
                src = mask; dst = cMask; v = t - 524288ull;
            } else {
                size_t j = t - 524800ull;        // 0..767, 128 vecs / segment
                int w = (int)(j >> 7);
                src = (w == 0) ? bq : (w == 1) ? bk : (w == 2) ? bv
                    : (w == 3) ? bo : (w == 4) ? g : be;
                dst = cB + w * 1024;
                v = j & 127;
            }
            if (f) {
                const float4* s4 = (const float4*)src;
                float4 a = s4[v * 2], b = s4[v * 2 + 1];
                union { ushort_t u[8]; uint4 q; } pk;
                pk.u[0] = f2bf(a.x); pk.u[1] = f2bf(a.y);
                pk.u[2] = f2bf(a.z); pk.u[3] = f2bf(a.w);
                pk.u[4] = f2bf(b.x); pk.u[5] = f2bf(b.y);
                pk.u[6] = f2bf(b.z); pk.u[7] = f2bf(b.w);
                ((uint4*)dst)[v] = pk.q;
            } else {
                ((uint4*)dst)[v] = ((const uint4*)src)[v];
            }
        }
    } else {
        int id2 = blockIdx.x - 1024;
        int z = id2 >> 10;
        int rem = id2 & 1023;
        int bx = rem & 31, by = rem >> 5;
        const void* W = (z == 0) ? Wq : (z == 1) ? Wk : (z == 2) ? Wv : Wo;
        ushort_t* T = wt + (size_t)z * Dd * Dd;
        int tx = tid & 31, ty = tid >> 5;
        int x = bx * 32 + tx;
        int y0 = by * 32;
        for (int i = 0; i < 4; i++) {
            int y = y0 + ty + i * 8;
            tile[ty + i * 8][tx] = f2bf(load_in(W, (size_t)y * Dd + x, f));
        }
        __syncthreads();
        int x2 = by * 32 + tx;
        int y20 = bx * 32;
        for (int i = 0; i < 4; i++) {
            int y = y20 + ty + i * 8;
            T[(size_t)y * Dd + x2] = tile[tx][ty + i * 8];
        }
    }
}

// ---------------------------------------------------------------------------
// Kernel 1: fused QKV projection. grid=(N/128, M/128, 3), block=256 (4 waves)
// Double-buffered global_load_lds(16B) staging. Q pre-scaled by 0.125*log2e.
// Epilogue: per-mt 32x128 chunk through LDS, coalesced 32B stores for ALL z
// (R11 measured direct Q/K register stores at ~+15us vs this — reverted).
// Q,K: [B,H,S,HD]; V transposed: [B,H,HD,S].
// ---------------------------------------------------------------------------
__global__ __launch_bounds__(256) void gemm_qkv(
    const ushort_t* __restrict__ X, const ushort_t* __restrict__ wt,
    const ushort_t* __restrict__ cB,
    ushort_t* __restrict__ Qb, ushort_t* __restrict__ Kb, ushort_t* __restrict__ Vtb) {
    const int z = blockIdx.z;
    const ushort_t* Wt = wt + (size_t)z * Dd * Dd;
    const ushort_t* bias = cB + z * 1024;

    __shared__ __align__(16) ushort_t smem[2][2][128 * 32];  // 32 KB

    const int tid = threadIdx.x;
    const int lane = tid & 63, wv = tid >> 6;
    const int quad = lane >> 4, l15 = lane & 15;
    const int wrow = (wv >> 1) * 64, wcol = (wv & 1) * 64;
    const int row0 = blockIdx.y * 128, col0 = blockIdx.x * 128;
    const int lrow = lane >> 2, lcol = (lane & 3) * 8;

    const f32x4 fzero = {0.f, 0.f, 0.f, 0.f};
    f32x4 acc[4][4];
    for (int mt = 0; mt < 4; mt++)
        for (int nt = 0; nt < 4; nt++) acc[mt][nt] = fzero;

    for (int j = 0; j < 2; j++) {
        int ch = wv * 2 + j;
        gload_lds16(&X[(size_t)(row0 + ch * 16 + lrow) * Dd + lcol],
                    &smem[0][0][ch * 512]);
        gload_lds16(&Wt[(size_t)(col0 + ch * 16 + lrow) * Dd + lcol],
                    &smem[0][1][ch * 512]);
    }

    for (int k0 = 0; k0 < Dd; k0 += 32) {
        const int buf = (k0 >> 5) & 1;
        __syncthreads();
        if (k0 + 32 < Dd) {
            for (int j = 0; j < 2; j++) {
                int ch = wv * 2 + j;
                gload_lds16(&X[(size_t)(row0 + ch * 16 + lrow) * Dd + k0 + 32 + lcol],
                            &smem[buf ^ 1][0][ch * 512]);
                gload_lds16(&Wt[(size_t)(col0 + ch * 16 + lrow) * Dd + k0 + 32 + lcol],
                            &smem[buf ^ 1][1][ch * 512]);
            }
        }
        const ushort_t* As = &smem[buf][0][0];
        const ushort_t* Bs = &smem[buf][1][0];
        bf16x8 af[4], bfr[4];
        for (int mt = 0; mt < 4; mt++)
            af[mt] = *(const bf16x8*)(&As[(wrow + mt * 16 + l15) * 32 + quad * 8]);
        for (int nt = 0; nt < 4; nt++)
            bfr[nt] = *(const bf16x8*)(&Bs[(wcol + nt * 16 + l15) * 32 + quad * 8]);
        for (int mt = 0; mt < 4; mt++)
            for (int nt = 0; nt < 4; nt++)
                acc[mt][nt] = __builtin_amdgcn_mfma_f32_16x16x32_bf16(
                    af[mt], bfr[nt], acc[mt][nt], 0, 0, 0);
    }

    // ---- epilogue: per-mt 32x128 chunk via LDS, coalesced 32B stores ----
    const float qscale = 0.18033688f;  // 0.125 * log2(e)
    ushort_t* Cs = &smem[0][0][0];
    for (int mt = 0; mt < 4; mt++) {
        __syncthreads();
        for (int nt = 0; nt < 4; nt++) {
            int gn = col0 + wcol + nt * 16 + l15;
            float bv_ = bf2f(bias[gn]);
            for (int r = 0; r < 4; r++) {
                float v = acc[mt][nt][r] + bv_;
                if (z == 0) v *= qscale;
                int ric = (wv >> 1) * 16 + quad * 4 + r;
                Cs[ric * 136 + wcol + nt * 16 + l15] = f2bf(v);
            }
        }
        __syncthreads();
        if (z == 2) {
            int c = tid >> 1, r0 = (tid & 1) * 16;
            int gn = col0 + c, h = gn >> 6, d = gn & 63;
            int gmbase = row0 + (r0 >> 4) * 64 + mt * 16;
            int b = gmbase >> 11, s0 = gmbase & 2047;
            union { ushort_t u[16]; uint4 q[2]; } pk;
            for (int i = 0; i < 16; i++) pk.u[i] = Cs[(r0 + i) * 136 + c];
            uint4* dst = (uint4*)&Vtb[((size_t)((b * Hh + h) * HD + d)) * Ss + s0];
            dst[0] = pk.q[0];
            dst[1] = pk.q[1];
        } else {
            int ric = tid >> 3, c0 = (tid & 7) * 16;
            int gm = row0 + (ric >> 4) * 64 + mt * 16 + (ric & 15);
            int gn = col0 + c0, h = gn >> 6, d0 = gn & 63;
            int b = gm >> 11, s = gm & 2047;
            const uint4* src = (const uint4*)&Cs[ric * 136 + c0];
            ushort_t* Ob = (z == 0) ? Qb : Kb;
            uint4* dst = (uint4*)&Ob[((size_t)((b * Hh + h) * Ss + s)) * HD + d0];
            dst[0] = src[0];
            dst[1] = src[1];
        }
    }
}

// ---------------------------------------------------------------------------
// Kernel 2: flash attention (R8 config — best measured). S^T orientation,
// streaming softmax (fixed shift in mask, cancelled by norm), mask as MFMA C
// operand, l via ones-column PV MFMA. grid=(B*H, S/128), block=512.
// ---------------------------------------------------------------------------
#define STR 76
__global__ __launch_bounds__(512) void attn(
    const ushort_t* __restrict__ Q, const ushort_t* __restrict__ K,
    const ushort_t* __restrict__ Vt, const ushort_t* __restrict__ mask,
    ushort_t* __restrict__ ctx) {
    const int tid = threadIdx.x;
    const int lane = tid & 63, wv = tid >> 6;
    const int quad = lane >> 4, l15 = lane & 15;
    const int bh = blockIdx.x;
    const int b = bh >> 4, h = bh & 15;
    const int q0 = blockIdx.y * 128 + wv * 16;

    const ushort_t* Qh = Q + (size_t)bh * Ss * HD;
    const ushort_t* Kh = K + (size_t)bh * Ss * HD;
    const ushort_t* Vh = Vt + (size_t)bh * HD * Ss;

    __shared__ __align__(16) ushort_t Ks[2][64 * 64];  // 16KB
    __shared__ __align__(16) ushort_t Vs[2][64 * 64];  // 16KB
    __shared__ __align__(16) float maskF[Ss];          // 8KB: (m-4)*log2e
    __shared__ __align__(16) ushort_t Pl[8][16 * STR]; // 19KB
    ushort_t* Pw = &Pl[wv][0];

    for (int i = tid; i < Ss; i += 512)
        maskF[i] = (bf2f(mask[b * Ss + i]) - 4.0f) * 1.4426950f;

    const int r8 = lane >> 3, c8 = lane & 7, gc = c8 ^ r8;  // XOR swizzle
    const int sw = l15 & 7;

    gload_lds16(&Kh[(size_t)(wv * 8 + r8) * HD + gc * 8], &Ks[0][wv * 512]);
    gload_lds16(&Vh[(size_t)(wv * 8 + r8) * Ss + gc * 8], &Vs[0][wv * 512]);

    bf16x8 qf[2];
    qf[0] = *(const bf16x8*)(&Qh[(size_t)(q0 + l15) * HD + quad * 8]);
    qf[1] = *(const bf16x8*)(&Qh[(size_t)(q0 + l15) * HD + 32 + quad * 8]);

    bf16x8 onesf;
    {
        union { ushort_t u[8]; bf16x8 v; } ou;
        for (int i = 0; i < 8; i++) ou.u[i] = 0x3F80;  // bf16 1.0
        onesf = ou.v;
    }

    const f32x4 fzero = {0.f, 0.f, 0.f, 0.f};
    f32x4 o[4];
    for (int dt = 0; dt < 4; dt++) o[dt] = fzero;
    f32x4 o_l = fzero;  // per-query sum of P (C-layout)

    for (int kb = 0; kb < Ss; kb += 64) {
        const int buf = (kb >> 6) & 1;
        __syncthreads();

        if (kb + 64 < Ss) {
            gload_lds16(&Kh[(size_t)(kb + 64 + wv * 8 + r8) * HD + gc * 8],
                        &Ks[buf ^ 1][wv * 512]);
            gload_lds16(&Vh[(size_t)(wv * 8 + r8) * Ss + kb + 64 + gc * 8],
                        &Vs[buf ^ 1][wv * 512]);
        }

        const ushort_t* ks = &Ks[buf][0];
        const ushort_t* vs = &Vs[buf][0];

        f32x4 st[4];
        for (int kt = 0; kt < 4; kt++) {
            f32x4 mk = *(const f32x4*)(&maskF[kb + kt * 16 + quad * 4]);
            bf16x8 kf0 = *(const bf16x8*)(&ks[(kt * 16 + l15) * 64 + ((quad) ^ sw) * 8]);
            bf16x8 kf1 = *(const bf16x8*)(&ks[(kt * 16 + l15) * 64 + ((quad + 4) ^ sw) * 8]);
            st[kt] = __builtin_amdgcn_mfma_f32_16x16x32_bf16(kf0, qf[0], mk, 0, 0, 0);
            st[kt] = __builtin_amdgcn_mfma_f32_16x16x32_bf16(kf1, qf[1], st[kt], 0, 0, 0);
        }

        for (int kt = 0; kt < 4; kt++) {
            float e0 = EXP2(st[kt][0]);
            float e1 = EXP2(st[kt][1]);
            float e2 = EXP2(st[kt][2]);
            float e3 = EXP2(st[kt][3]);
            uint2 pk;
            pk.x = __builtin_amdgcn_perm(fbits(e1), fbits(e0), 0x07060302u);
            pk.y = __builtin_amdgcn_perm(fbits(e3), fbits(e2), 0x07060302u);
            *(uint2*)(&Pw[l15 * STR + kt * 16 + quad * 4]) = pk;
        }

        for (int c = 0; c < 2; c++) {
            union { uint2 u2[2]; bf16x8 v; } pu;
            pu.u2[0] = *(const uint2*)(&Pw[l15 * STR + c * 32 + quad * 8]);
            pu.u2[1] = *(const uint2*)(&Pw[l15 * STR + c * 32 + quad * 8 + 4]);
            bf16x8 pf = pu.v;
            for (int dt = 0; dt < 4; dt++) {
                bf16x8 vf = *(const bf16x8*)(
                    &vs[(dt * 16 + l15) * 64 + ((c * 4 + quad) ^ sw) * 8]);
                o[dt] = __builtin_amdgcn_mfma_f32_16x16x32_bf16(pf, vf, o[dt], 0, 0, 0);
            }
            o_l = __builtin_amdgcn_mfma_f32_16x16x32_bf16(pf, onesf, o_l, 0, 0, 0);
        }
    }

    for (int r = 0; r < 4; r++) {
        int q = q0 + quad * 4 + r;
        float linv = 1.f / o_l[r];
        for (int dt = 0; dt < 4; dt++) {
            ctx[((size_t)(b * Ss + q)) * Dd + h * HD + dt * 16 + l15] =
                f2bf(o[dt][r] * linv);
        }
    }
}

// ---------------------------------------------------------------------------
// Kernel 3: output projection + bias + residual -> bf16 x buffer.
// 64x128 tiles, grid=(8,64)=512 blocks; double-buffered staging.
// ---------------------------------------------------------------------------
__global__ __launch_bounds__(256) void gemm_out(
    const ushort_t* __restrict__ A, const ushort_t* __restrict__ Wt,
    const ushort_t* __restrict__ bo, const ushort_t* __restrict__ X,
    ushort_t* __restrict__ xout) {
    __shared__ __align__(16) ushort_t smem[2][6144];  // 24 KB

    const int tid = threadIdx.x;
    const int lane = tid & 63, wv = tid >> 6;
    const int quad = lane >> 4, l15 = lane & 15;
    const int wrow = (wv >> 1) * 32, wcol = (wv & 1) * 64;
    const int row0 = blockIdx.y * 64, col0 = blockIdx.x * 128;
    const int lrow = lane >> 2, lcol = (lane & 3) * 8;

    const f32x4 fzero = {0.f, 0.f, 0.f, 0.f};
    f32x4 acc[2][4];
    for (int mt = 0; mt < 2; mt++)
        for (int nt = 0; nt < 4; nt++) acc[mt][nt] = fzero;

    gload_lds16(&A[(size_t)(row0 + wv * 16 + lrow) * Dd + lcol], &smem[0][wv * 512]);
    for (int j = 0; j < 2; j++) {
        int ch = wv * 2 + j;
        gload_lds16(&Wt[(size_t)(col0 + ch * 16 + lrow) * Dd + lcol],
                    &smem[0][2048 + ch * 512]);
    }

    for (int k0 = 0; k0 < Dd; k0 += 32) {
        const int buf = (k0 >> 5) & 1;
        __syncthreads();
        if (k0 + 32 < Dd) {
            gload_lds16(&A[(size_t)(row0 + wv * 16 + lrow) * Dd + k0 + 32 + lcol],
                        &smem[buf ^ 1][wv * 512]);
            for (int j = 0; j < 2; j++) {
                int ch = wv * 2 + j;
                gload_lds16(&Wt[(size_t)(col0 + ch * 16 + lrow) * Dd + k0 + 32 + lcol],
                            &smem[buf ^ 1][2048 + ch * 512]);
            }
        }
        const ushort_t* As = &smem[buf][0];
        const ushort_t* Bs = &smem[buf][2048];
        bf16x8 af[2], bfr[4];
        for (int mt = 0; mt < 2; mt++)
            af[mt] = *(const bf16x8*)(&As[(wrow + mt * 16 + l15) * 32 + quad * 8]);
        for (int nt = 0; nt < 4; nt++)
            bfr[nt] = *(const bf16x8*)(&Bs[(wcol + nt * 16 + l15) * 32 + quad * 8]);
        for (int mt = 0; mt < 2; mt++)
            for (int nt = 0; nt < 4; nt++)
                acc[mt][nt] = __builtin_amdgcn_mfma_f32_16x16x32_bf16(
                    af[mt], bfr[nt], acc[mt][nt], 0, 0, 0);
    }

    for (int mt = 0; mt < 2; mt++)
        for (int nt = 0; nt < 4; nt++)
            for (int r = 0; r < 4; r++) {
                int gm = row0 + wrow + mt * 16 + quad * 4 + r;
                int gn = col0 + wcol + nt * 16 + l15;
                float v = acc[mt][nt][r] + bf2f(bo[gn]) + bf2f(X[(size_t)gm * Dd + gn]);
                xout[(size_t)gm * Dd + gn] = f2bf(v);
            }
}

// ---------------------------------------------------------------------------
// Kernel 4: LayerNorm over rows of x (bf16) -> out (dtype per flag).
// ---------------------------------------------------------------------------
__global__ __launch_bounds__(256) void ln_k(
    const ushort_t* __restrict__ x, const ushort_t* __restrict__ gamma,
    const ushort_t* __restrict__ beta, const int* __restrict__ flag,
    void* __restrict__ out) {
    const int row = blockIdx.x;
    const int tid = threadIdx.x;
    const int f = *flag;

    union { uint2 q; ushort_t u[4]; } xv;
    xv.q = ((const uint2*)(x + (size_t)row * Dd))[tid];
    float xi[4];
    for (int i = 0; i < 4; i++) xi[i] = bf2f(xv.u[i]);
    float s = (xi[0] + xi[1]) + (xi[2] + xi[3]);
    float ss = (xi[0] * xi[0] + xi[1] * xi[1]) + (xi[2] * xi[2] + xi[3] * xi[3]);
    for (int off = 1; off < 64; off <<= 1) {
        s += __shfl_xor(s, off);
        ss += __shfl_xor(ss, off);
    }
    __shared__ float ps[4], pss[4];
    int wv = tid >> 6;
    if ((tid & 63) == 0) { ps[wv] = s; pss[wv] = ss; }
    __syncthreads();
    s = ps[0] + ps[1] + ps[2] + ps[3];
    ss = pss[0] + pss[1] + pss[2] + pss[3];
    float mu = s * (1.f / Dd);
    float var = ss * (1.f / Dd) - mu * mu;
    float rstd = rsqrtf(fmaxf(var, 0.f) + 1e-12f);

    const int c0 = tid * 4;
    float r[4];
    for (int i = 0; i < 4; i++) {
        float g = bf2f(gamma[c0 + i]);
        float bb = bf2f(beta[c0 + i]);
        r[i] = (xi[i] - mu) * rstd * g + bb;
    }
    if (f) {
        float4 o4 = {r[0], r[1], r[2], r[3]};
        ((float4*)out)[(size_t)row * 256 + tid] = o4;
    } else {
        union { ushort_t u[4]; uint2 q; } pk;
        for (int i = 0; i < 4; i++) pk.u[i] = f2bf(r[i]);
        *(uint2*)((ushort_t*)out + (size_t)row * Dd + c0) = pk.q;
    }
}

// ---------------------------------------------------------------------------
extern "C" void kernel_launch(void* const* d_in, const int* in_sizes, int n_in,
                              void* d_out, int out_size, void* d_ws, size_t ws_size,
                              hipStream_t stream) {
    char* ws = (char*)d_ws;
    int* flag       = (int*)ws;                          // @0
    ushort_t* cMask = (ushort_t*)(ws + (64ull << 10));   // @64KB  (8KB)
    ushort_t* cB    = (ushort_t*)(ws + (96ull << 10));   // @96KB  (12KB)
    ushort_t* cX    = (ushort_t*)(ws + (1ull << 20));    // @1MB   (8MB)
    ushort_t* wt    = (ushort_t*)(ws + (17ull << 20));   // @17MB  (8MB)
    ushort_t* Qb    = (ushort_t*)(ws + (25ull << 20));   // @25MB  (8MB)
    ushort_t* Kb    = (ushort_t*)(ws + (33ull << 20));   // @33MB  (8MB)
    ushort_t* Vtb   = (ushort_t*)(ws + (41ull << 20));   // @41MB  (8MB)
    ushort_t* ctx   = (ushort_t*)(ws + (49ull << 20));   // @49MB  (8MB)
    ushort_t* xbuf  = (ushort_t*)(ws + (25ull << 20));   // reuse Qb (8MB bf16)

    hipLaunchKernelGGL(prep_k, dim3(5120), dim3(256), 0, stream,
                       d_in[0], d_in[1], d_in[3], d_in[5], d_in[7], d_in[9],
                       d_in[10], d_in[11], d_in[2], d_in[4], d_in[6], d_in[8],
                       flag, cX, cMask, cB, wt);
    hipLaunchKernelGGL(gemm_qkv, dim3(8, 32, 3), dim3(256), 0, stream,
                       cX, wt, cB, Qb, Kb, Vtb);
    hipLaunchKernelGGL(attn, dim3(32, 16), dim3(512), 0, stream,
                       Qb, Kb, Vtb, cMask, ctx);
    hipLaunchKernelGGL(gemm_out, dim3(8, 64), dim3(256), 0, stream,
                       ctx, wt + 3ull * Dd * Dd, cB + 3 * 1024, cX, xbuf);
    hipLaunchKernelGGL(ln_k, dim3(Mtot), dim3(256), 0, stream,
                       xbuf, cB + 4 * 1024, cB + 5 * 1024, flag, d_out);
}